// Round 5
// baseline (334.712 us; speedup 1.0000x reference)
//
#include <hip/hip_runtime.h>

// VQ-VAE VectorQuantizer forward, MI355X (gfx950)
// Round 5: codes-resident-in-LDS, x-streaming, barrier-free main loop,
//          cross-slice merge in a second kernel.
// inputs: d_in[0] = x (65536 x 64 f32), d_in[1] = w (1024 x 64 f32)
// out (f32 flat): [0..4194304) quantized, [4194304] loss,
//                 [4194305..+65536) indices (as float), [4259841..+65536) w.T

#define N_VEC 65536
#define D 64
#define K 1024
#define BETA 0.25f

#define OFF_Q    0
#define OFF_LOSS 4194304
#define OFF_IDX  4194305
#define OFF_WT   4259841

// ws layout (bytes): frag-ordered fp16 codebook + (-0.5*||w||^2). 264 KB total
// (same footprint as rounds 3/4 — proven to fit ws).
#define WS_WHI  0         // 128 KB
#define WS_WLO  131072    // 128 KB
#define WS_HNEG 262144    // 4 KB

typedef _Float16 v8h __attribute__((ext_vector_type(8)));
typedef float v16f __attribute__((ext_vector_type(16)));
typedef __attribute__((address_space(3))) void lds_void_t;
typedef __attribute__((address_space(1))) const void gbl_void_t;

// ---------------- prep (unchanged from round 4): w^T, frag-ordered fp16 hi/lo,
// -0.5||w||^2, loss=0. Block t owns codes 32t..32t+31.
__global__ __launch_bounds__(256) void vq_prep(const float* __restrict__ w,
                                               char* __restrict__ ws,
                                               float* __restrict__ out) {
  __shared__ float s[2048];
  const int t = blockIdx.x, tid = threadIdx.x;

  const float4* src = (const float4*)(w + (size_t)t * 2048);
  float4 a = src[tid];
  float4 b = src[tid + 256];
  ((float4*)s)[tid] = a;
  ((float4*)s)[tid + 256] = b;

  float p0 = a.x * a.x + a.y * a.y + a.z * a.z + a.w * a.w;
  float p1 = b.x * b.x + b.y * b.y + b.z * b.z + b.w * b.w;
#pragma unroll
  for (int m = 1; m <= 8; m <<= 1) {
    p0 += __shfl_xor(p0, m, 64);
    p1 += __shfl_xor(p1, m, 64);
  }
  float* hn = (float*)(ws + WS_HNEG);
  if ((tid & 15) == 0) {
    hn[t * 32 + (tid >> 4)] = -0.5f * p0;
    hn[t * 32 + 16 + (tid >> 4)] = -0.5f * p1;
  }
  if (t == 0 && tid == 0) out[OFF_LOSS] = 0.f;
  __syncthreads();

  { // frag order: byte ((t*4+ks)*64 + l)*16 + 2j  <->  w[t*32+(l&31)][ks*16+(l>>5)*8+j]
    const int ks = tid >> 6, l = tid & 63;
    const float* r0 = s + (l & 31) * 64 + ks * 16 + ((l >> 5) << 3);
    v8h hv, lv;
#pragma unroll
    for (int j = 0; j < 8; ++j) {
      float v = r0[j];
      _Float16 h = (_Float16)v;
      hv[j] = h;
      lv[j] = (_Float16)(v - (float)h);
    }
    const size_t eoff = ((size_t)(t * 4 + ks) * 64 + l) * 16;
    *(v8h*)(ws + WS_WHI + eoff) = hv;
    *(v8h*)(ws + WS_WLO + eoff) = lv;
  }

  { // w^T
    const int d = tid >> 2, k0 = (tid & 3) * 8;
#pragma unroll
    for (int j = 0; j < 8; ++j)
      out[OFF_WT + d * 1024 + t * 32 + k0 + j] = s[(k0 + j) * 64 + d];
  }
}

// ---------------- scan: grid 512 = 128 row-groups x 4 slices. Block: 4 waves,
// slice of 256 codes resident in LDS (staged once). Wave: 2 passes x 2 x-tiles.
// Partials (score, idx) + ||x||^2 written into each row's quantized slot
// (floats 0..8 of out[row*64]), overwritten by vq_merge.
#define SLICES  4
#define ROWS_PB 512

__global__ __launch_bounds__(256, 2) void vq_scan(const float* __restrict__ x,
                                                  const char* __restrict__ ws,
                                                  float* __restrict__ out) {
  __shared__ __align__(16) char lds[66560];   // 32K hi + 32K lo + 1K hneg
  const int tid = threadIdx.x;
  const int wv = tid >> 6, ln = tid & 63;
  const int col = ln & 31, hi = ln >> 5;
  const int slice = blockIdx.x & 3;
  const int rowsBlock = (blockIdx.x >> 2) * ROWS_PB;

  // ---- stage slice once: uniform LDS base + per-lane global (m104-safe)
  {
    const char* gH = ws + WS_WHI + slice * 32768;
    const char* gL = ws + WS_WLO + slice * 32768;
#pragma unroll
    for (int it = 0; it < 8; ++it) {
      const unsigned off = (unsigned)(it * 4096 + wv * 1024);
      __builtin_amdgcn_global_load_lds((gbl_void_t*)(gH + off + ln * 16),
                                       (lds_void_t*)(lds + off), 16, 0, 0);
      __builtin_amdgcn_global_load_lds((gbl_void_t*)(gL + off + ln * 16),
                                       (lds_void_t*)(lds + 32768 + off), 16, 0, 0);
    }
    if (wv == 0)
      __builtin_amdgcn_global_load_lds((gbl_void_t*)(ws + WS_HNEG + slice * 1024 + ln * 16),
                                       (lds_void_t*)(lds + 65536), 16, 0, 0);
  }
  asm volatile("s_waitcnt vmcnt(0)" ::: "memory");
  __syncthreads();                 // the ONLY barrier in this kernel

  const float* hn = (const float*)(lds + 65536);

#pragma unroll 1
  for (int p = 0; p < 2; ++p) {
    const int rows0 = rowsBlock + wv * 128 + p * 64;   // tile0: rows0, tile1: rows0+32

    // ---- A-frags (x) for 2 tiles: fp16 hi/lo split + ||x||^2
    v8h ah0[4], al0[4], ah1[4], al1[4];
    float xn0 = 0.f, xn1 = 0.f;
    {
      const float* xr0 = x + (size_t)(rows0 + col) * D + hi * 8;
      const float* xr1 = x + (size_t)(rows0 + 32 + col) * D + hi * 8;
#pragma unroll
      for (int ks = 0; ks < 4; ++ks) {
        float4 u0 = *(const float4*)(xr0 + ks * 16);
        float4 u1 = *(const float4*)(xr0 + ks * 16 + 4);
        float4 v0 = *(const float4*)(xr1 + ks * 16);
        float4 v1 = *(const float4*)(xr1 + ks * 16 + 4);
        float e0[8] = {u0.x, u0.y, u0.z, u0.w, u1.x, u1.y, u1.z, u1.w};
        float e1[8] = {v0.x, v0.y, v0.z, v0.w, v1.x, v1.y, v1.z, v1.w};
#pragma unroll
        for (int j = 0; j < 8; ++j) {
          _Float16 h0 = (_Float16)e0[j];
          ah0[ks][j] = h0;
          al0[ks][j] = (_Float16)(e0[j] - (float)h0);
          xn0 = fmaf(e0[j], e0[j], xn0);
          _Float16 h1 = (_Float16)e1[j];
          ah1[ks][j] = h1;
          al1[ks][j] = (_Float16)(e1[j] - (float)h1);
          xn1 = fmaf(e1[j], e1[j], xn1);
        }
      }
    }
    xn0 += __shfl_xor(xn0, 32, 64);   // lanes ln / ln+32 hold complementary halves
    xn1 += __shfl_xor(xn1, 32, 64);

    v16f best0, best1;
    int bi0[16], bi1[16];
#pragma unroll
    for (int r = 0; r < 16; ++r) {
      best0[r] = -3.0e38f; best1[r] = -3.0e38f; bi0[r] = 0; bi1[r] = 0;
    }

    // ---- scan the slice: 8 ctiles x (4 ks x 6 MFMA), B-frags shared by both tiles
#pragma unroll
    for (int ct = 0; ct < 8; ++ct) {
      const float h = hn[ct * 32 + col];
      v16f acc0, acc1;
#pragma unroll
      for (int r = 0; r < 16; ++r) { acc0[r] = h; acc1[r] = h; }
#pragma unroll
      for (int ks = 0; ks < 4; ++ks) {
        v8h bh = *(const v8h*)(lds + ct * 4096 + ks * 1024 + ln * 16);
        v8h bl = *(const v8h*)(lds + 32768 + ct * 4096 + ks * 1024 + ln * 16);
        acc0 = __builtin_amdgcn_mfma_f32_32x32x16_f16(ah0[ks], bh, acc0, 0, 0, 0);
        acc1 = __builtin_amdgcn_mfma_f32_32x32x16_f16(ah1[ks], bh, acc1, 0, 0, 0);
        acc0 = __builtin_amdgcn_mfma_f32_32x32x16_f16(al0[ks], bh, acc0, 0, 0, 0);
        acc1 = __builtin_amdgcn_mfma_f32_32x32x16_f16(al1[ks], bh, acc1, 0, 0, 0);
        acc0 = __builtin_amdgcn_mfma_f32_32x32x16_f16(ah0[ks], bl, acc0, 0, 0, 0);
        acc1 = __builtin_amdgcn_mfma_f32_32x32x16_f16(ah1[ks], bl, acc1, 0, 0, 0);
      }
      const int kg = slice * 256 + ct * 32 + col;   // ascending => strict > keeps first
#pragma unroll
      for (int r = 0; r < 16; ++r) {
        if (acc0[r] > best0[r]) { best0[r] = acc0[r]; bi0[r] = kg; }
        if (acc1[r] > best1[r]) { best1[r] = acc1[r]; bi1[r] = kg; }
      }
    }

    // ---- cross-lane argmax over the 32 code-cols (stays within each hi-half)
#pragma unroll
    for (int m = 1; m <= 16; m <<= 1) {
#pragma unroll
      for (int r = 0; r < 16; ++r) {
        float ov = __shfl_xor(best0[r], m, 64);
        int oi = __shfl_xor(bi0[r], m, 64);
        if (ov > best0[r] || (ov == best0[r] && oi < bi0[r])) { best0[r] = ov; bi0[r] = oi; }
        ov = __shfl_xor(best1[r], m, 64);
        oi = __shfl_xor(bi1[r], m, 64);
        if (ov > best1[r] || (ov == best1[r] && oi < bi1[r])) { best1[r] = ov; bi1[r] = oi; }
      }
    }

    // ---- publish partials into each row's quantized slot: floats [slice*2, +2)
    if (col == 0) {                      // lanes 0 and 32 (hi = 0 / 1)
#pragma unroll
      for (int r = 0; r < 16; ++r) {
        const int rmap = (r & 3) + 8 * (r >> 2) + 4 * hi;   // C/D row map
        *(float2*)(out + (size_t)(rows0 + rmap) * 64 + slice * 2) =
            make_float2(best0[r], (float)bi0[r]);
        *(float2*)(out + (size_t)(rows0 + 32 + rmap) * 64 + slice * 2) =
            make_float2(best1[r], (float)bi1[r]);
      }
    }
    if (slice == 0 && hi == 0) {         // ||x||^2 at float 8 of the row slot
      out[(size_t)(rows0 + col) * 64 + 8] = xn0;
      out[(size_t)(rows0 + 32 + col) * 64 + 8] = xn1;
    }
  }
}

// ---------------- merge: 4 threads per row (same wave). Reads partials from the
// row's slot, picks winner (tie -> smallest idx == jnp.argmax), overwrites the
// slot with quantized, writes idx, accumulates loss = sum(xnorm - 2*score).
__global__ __launch_bounds__(256) void vq_merge(const float* __restrict__ w,
                                                float* __restrict__ out) {
  const int t = blockIdx.x * 256 + threadIdx.x;   // 262144 threads
  const int row = t >> 2, p = t & 3;
  const int ln = threadIdx.x & 63;
  float* pb = out + (size_t)row * 64;

  float2 cand = *(const float2*)(pb + p * 2);     // slice p's (score, idx)
  float xn = pb[8];
  float s = cand.x, fi = cand.y;
#pragma unroll
  for (int m = 1; m <= 2; m <<= 1) {              // reduce across the 4 slices
    float os = __shfl_xor(s, m, 64);
    float ofi = __shfl_xor(fi, m, 64);
    if (os > s || (os == s && ofi < fi)) { s = os; fi = ofi; }
  }
  const int bi = (int)fi;
  if (p == 0) out[OFF_IDX + row] = fi;

  const float4* qs = (const float4*)(w + (size_t)bi * D + p * 16);
  float4 q0 = qs[0], q1 = qs[1], q2 = qs[2], q3 = qs[3];
  float4* qd = (float4*)(pb + p * 16);            // overwrites partial bytes
  qd[0] = q0; qd[1] = q1; qd[2] = q2; qd[3] = q3;

  float lr = (p == 0) ? (xn - 2.f * s) : 0.f;     // ||x-w||^2 = ||x||^2 - 2*score
#pragma unroll
  for (int off = 32; off >= 1; off >>= 1) lr += __shfl_xor(lr, off, 64);
  if (ln == 0) atomicAdd(out + OFF_LOSS, lr * (BETA / (float)(N_VEC * D)));
}

extern "C" void kernel_launch(void* const* d_in, const int* in_sizes, int n_in,
                              void* d_out, int out_size, void* d_ws, size_t ws_size,
                              hipStream_t stream) {
  const float* x = (const float*)d_in[0];
  const float* w = (const float*)d_in[1];
  float* out = (float*)d_out;
  char* ws = (char*)d_ws;

  vq_prep<<<32, 256, 0, stream>>>(w, ws, out);
  vq_scan<<<(N_VEC / ROWS_PB) * SLICES, 256, 0, stream>>>(x, ws, out);
  vq_merge<<<N_VEC * 4 / 256, 256, 0, stream>>>(w, out);
}

// Round 6
// 118.758 us; speedup vs baseline: 2.8184x; 2.8184x over previous
//
#include <hip/hip_runtime.h>

// VQ-VAE VectorQuantizer forward, MI355X (gfx950)
// Round 6: swapped-operand MFMA (A=w codes, B=x rows) -> per-lane scalar argmax,
//          bias-MFMA for -0.5||w||^2, codes-resident LDS, coalesced partials,
//          self-contained 512-row merge blocks.
// out (f32 flat): [0..4194304) quantized, [4194304] loss,
//                 [4194305..+65536) indices (as float), [4259841..+65536) w.T

#define N_VEC 65536
#define D 64
#define K 1024
#define BETA 0.25f

#define OFF_Q    0
#define OFF_LOSS 4194304
#define OFF_IDX  4194305
#define OFF_WT   4259841

#define WS_WHI  0         // 128 KB frag-ordered fp16 hi plane
#define WS_WLO  131072    // 128 KB lo plane
#define WS_HNEG 262144    // 4 KB  -0.5*||w||^2 (f32)

typedef _Float16 v8h __attribute__((ext_vector_type(8)));
typedef float v16f __attribute__((ext_vector_type(16)));
typedef __attribute__((address_space(3))) void lds_void_t;
typedef __attribute__((address_space(1))) const void gbl_void_t;

// ---------------- prep (proven, unchanged): w^T, frag fp16 hi/lo, hneg, loss=0
__global__ __launch_bounds__(256) void vq_prep(const float* __restrict__ w,
                                               char* __restrict__ ws,
                                               float* __restrict__ out) {
  __shared__ float s[2048];
  const int t = blockIdx.x, tid = threadIdx.x;

  const float4* src = (const float4*)(w + (size_t)t * 2048);
  float4 a = src[tid];
  float4 b = src[tid + 256];
  ((float4*)s)[tid] = a;
  ((float4*)s)[tid + 256] = b;

  float p0 = a.x * a.x + a.y * a.y + a.z * a.z + a.w * a.w;
  float p1 = b.x * b.x + b.y * b.y + b.z * b.z + b.w * b.w;
#pragma unroll
  for (int m = 1; m <= 8; m <<= 1) {
    p0 += __shfl_xor(p0, m, 64);
    p1 += __shfl_xor(p1, m, 64);
  }
  float* hn = (float*)(ws + WS_HNEG);
  if ((tid & 15) == 0) {
    hn[t * 32 + (tid >> 4)] = -0.5f * p0;
    hn[t * 32 + 16 + (tid >> 4)] = -0.5f * p1;
  }
  if (t == 0 && tid == 0) out[OFF_LOSS] = 0.f;
  __syncthreads();

  { // frag order: ((t*4+ks)*64 + l)*16B <-> w[t*32+(l&31)][ks*16+(l>>5)*8+j]
    const int ks = tid >> 6, l = tid & 63;
    const float* r0 = s + (l & 31) * 64 + ks * 16 + ((l >> 5) << 3);
    v8h hv, lv;
#pragma unroll
    for (int j = 0; j < 8; ++j) {
      float v = r0[j];
      _Float16 h = (_Float16)v;
      hv[j] = h;
      lv[j] = (_Float16)(v - (float)h);
    }
    const size_t eoff = ((size_t)(t * 4 + ks) * 64 + l) * 16;
    *(v8h*)(ws + WS_WHI + eoff) = hv;
    *(v8h*)(ws + WS_WLO + eoff) = lv;
  }

  { // w^T
    const int d = tid >> 2, k0 = (tid & 3) * 8;
#pragma unroll
    for (int j = 0; j < 8; ++j)
      out[OFF_WT + d * 1024 + t * 32 + k0 + j] = s[(k0 + j) * 64 + d];
  }
}

// ---------------- scan: 512 blocks = 128 row-groups x 4 slices. 4 waves/block.
// Slice (256 codes) resident in LDS. Wave: 2 pass-pairs x 2 x-tiles x 32 rows.
// Partials -> LDS -> coalesced compact chunks in the quantized region:
//   group g floats [g*32768): [slice*1024, +1024) = 512 x (score, idxf); [4096, +512) = xn
#define ROWS_PB 512

__global__ __launch_bounds__(256, 2) void vq_scan(const float* __restrict__ x,
                                                  const char* __restrict__ ws,
                                                  float* __restrict__ out) {
  __shared__ __align__(16) char lds[72704];
  const int tid = threadIdx.x;
  const int wv = tid >> 6, ln = tid & 63;
  const int col = ln & 31, hi = ln >> 5;
  const int slice = blockIdx.x & 3;
  const int rowsBlock = (blockIdx.x >> 2) * ROWS_PB;

  // ---- stage slice once (wave-uniform LDS base + per-lane global)
  {
    const char* gH = ws + WS_WHI + slice * 32768;
    const char* gL = ws + WS_WLO + slice * 32768;
#pragma unroll
    for (int it = 0; it < 8; ++it) {
      const unsigned off = (unsigned)(it * 4096 + wv * 1024);
      __builtin_amdgcn_global_load_lds((gbl_void_t*)(gH + off + ln * 16),
                                       (lds_void_t*)(lds + off), 16, 0, 0);
      __builtin_amdgcn_global_load_lds((gbl_void_t*)(gL + off + ln * 16),
                                       (lds_void_t*)(lds + 32768 + off), 16, 0, 0);
    }
    if (wv == 0)
      __builtin_amdgcn_global_load_lds((gbl_void_t*)(ws + WS_HNEG + slice * 1024 + ln * 16),
                                       (lds_void_t*)(lds + 65536), 16, 0, 0);
  }
  asm volatile("s_waitcnt vmcnt(0)" ::: "memory");
  __syncthreads();

  const float* hn = (const float*)(lds + 65536);
  float2* s_part = (float2*)(lds + 66560);
  float* s_xn = (float*)(lds + 70656);

  // ones B-frag for the bias MFMA: B[k][*]=1 at k=0,1
  v8h ones = {};
  ones[0] = hi ? (_Float16)0.f : (_Float16)1.f;
  ones[1] = hi ? (_Float16)0.f : (_Float16)1.f;

#pragma unroll 1
  for (int pp = 0; pp < 2; ++pp) {
    const int rows0 = rowsBlock + wv * 128 + pp * 64;

    // ---- x B-frags for 2 tiles (fp16 hi/lo split) + ||x||^2 partials
    v8h xh0[4], xl0[4], xh1[4], xl1[4];
    float xn0 = 0.f, xn1 = 0.f;
    {
      const float* xr0 = x + (size_t)(rows0 + col) * D + hi * 8;
      const float* xr1 = x + (size_t)(rows0 + 32 + col) * D + hi * 8;
#pragma unroll
      for (int ks = 0; ks < 4; ++ks) {
        float4 u0 = *(const float4*)(xr0 + ks * 16);
        float4 u1 = *(const float4*)(xr0 + ks * 16 + 4);
        float4 v0 = *(const float4*)(xr1 + ks * 16);
        float4 v1 = *(const float4*)(xr1 + ks * 16 + 4);
        float e0[8] = {u0.x, u0.y, u0.z, u0.w, u1.x, u1.y, u1.z, u1.w};
        float e1[8] = {v0.x, v0.y, v0.z, v0.w, v1.x, v1.y, v1.z, v1.w};
#pragma unroll
        for (int j = 0; j < 8; ++j) {
          _Float16 h0 = (_Float16)e0[j];
          xh0[ks][j] = h0;
          xl0[ks][j] = (_Float16)(e0[j] - (float)h0);
          xn0 = fmaf(e0[j], e0[j], xn0);
          _Float16 h1 = (_Float16)e1[j];
          xh1[ks][j] = h1;
          xl1[ks][j] = (_Float16)(e1[j] - (float)h1);
          xn1 = fmaf(e1[j], e1[j], xn1);
        }
      }
    }

    float best0 = -3.0e38f, best1 = -3.0e38f;
    int bi0 = 0, bi1 = 0;

#pragma unroll 2
    for (int ct = 0; ct < 8; ++ct) {
      // w A-frags (shared by both tiles): A[code=l&31][k]
      v8h wh[4], wl[4];
#pragma unroll
      for (int ks = 0; ks < 4; ++ks) {
        wh[ks] = *(const v8h*)(lds + ct * 4096 + ks * 1024 + ln * 16);
        wl[ks] = *(const v8h*)(lds + 32768 + ct * 4096 + ks * 1024 + ln * 16);
      }
      // bias A-frag: A[code][0]=hn_hi, A[code][1]=hn_lo (fp16 split of f32 hneg)
      const float hv = hn[ct * 32 + col];
      const _Float16 bh = (_Float16)hv;
      const _Float16 bl = (_Float16)(hv - (float)bh);
      v8h bias = {};
      bias[0] = hi ? (_Float16)0.f : bh;
      bias[1] = hi ? (_Float16)0.f : bl;

      v16f a0 = {}, a1 = {};
      a0 = __builtin_amdgcn_mfma_f32_32x32x16_f16(bias, ones, a0, 0, 0, 0);
      a1 = __builtin_amdgcn_mfma_f32_32x32x16_f16(bias, ones, a1, 0, 0, 0);
#pragma unroll
      for (int ks = 0; ks < 4; ++ks) {
        a0 = __builtin_amdgcn_mfma_f32_32x32x16_f16(wh[ks], xh0[ks], a0, 0, 0, 0);
        a1 = __builtin_amdgcn_mfma_f32_32x32x16_f16(wh[ks], xh1[ks], a1, 0, 0, 0);
        a0 = __builtin_amdgcn_mfma_f32_32x32x16_f16(wl[ks], xh0[ks], a0, 0, 0, 0);
        a1 = __builtin_amdgcn_mfma_f32_32x32x16_f16(wl[ks], xh1[ks], a1, 0, 0, 0);
        a0 = __builtin_amdgcn_mfma_f32_32x32x16_f16(wh[ks], xl0[ks], a0, 0, 0, 0);
        a1 = __builtin_amdgcn_mfma_f32_32x32x16_f16(wh[ks], xl1[ks], a1, 0, 0, 0);
      }

      // per-lane argmax over this ct's 16 codes (codes ascend with r)
      float m0 = fmaxf(fmaxf(fmaxf(a0[0], a0[1]), fmaxf(a0[2], a0[3])),
                       fmaxf(fmaxf(a0[4], a0[5]), fmaxf(a0[6], a0[7])));
      m0 = fmaxf(m0, fmaxf(fmaxf(fmaxf(a0[8], a0[9]), fmaxf(a0[10], a0[11])),
                           fmaxf(fmaxf(a0[12], a0[13]), fmaxf(a0[14], a0[15]))));
      float m1 = fmaxf(fmaxf(fmaxf(a1[0], a1[1]), fmaxf(a1[2], a1[3])),
                       fmaxf(fmaxf(a1[4], a1[5]), fmaxf(a1[6], a1[7])));
      m1 = fmaxf(m1, fmaxf(fmaxf(fmaxf(a1[8], a1[9]), fmaxf(a1[10], a1[11])),
                           fmaxf(fmaxf(a1[12], a1[13]), fmaxf(a1[14], a1[15]))));
      const bool u0 = m0 > best0;
      const bool u1 = m1 > best1;
      if (__any(u0 || u1)) {
        const int cbase = slice * 256 + ct * 32 + 4 * hi;
#pragma unroll
        for (int r = 15; r >= 0; --r) {   // descending overwrite => first max wins
          const int code = cbase + (r & 3) + 8 * (r >> 2);
          bi0 = (u0 && a0[r] == m0) ? code : bi0;
          bi1 = (u1 && a1[r] == m1) ? code : bi1;
        }
        best0 = u0 ? m0 : best0;
        best1 = u1 ? m1 : best1;
      }
    }

    // ---- merge the two hi-halves (each covered 16 of 32 codes per ct)
    {
      float ob = __shfl_xor(best0, 32, 64);
      int oi = __shfl_xor(bi0, 32, 64);
      if (ob > best0 || (ob == best0 && oi < bi0)) { best0 = ob; bi0 = oi; }
      ob = __shfl_xor(best1, 32, 64);
      oi = __shfl_xor(bi1, 32, 64);
      if (ob > best1 || (ob == best1 && oi < bi1)) { best1 = ob; bi1 = oi; }
      xn0 += __shfl_xor(xn0, 32, 64);
      xn1 += __shfl_xor(xn1, 32, 64);
    }

    // ---- publish: lo-lanes write tile0's row, hi-lanes tile1's
    const int rl = wv * 128 + pp * 64 + hi * 32 + col;
    s_part[rl] = make_float2(hi ? best1 : best0, (float)(hi ? bi1 : bi0));
    if (slice == 0) s_xn[rl] = hi ? xn1 : xn0;
  }
  __syncthreads();

  // ---- coalesced publish of compact partial chunks
  float* outP = out + (size_t)rowsBlock * 64;
  ((float4*)(outP + slice * 1024))[tid] = ((const float4*)s_part)[tid];
  if (slice == 0 && tid < 128)
    ((float4*)(outP + 4096))[tid] = ((const float4*)s_xn)[tid];
}

// ---------------- merge: 128 self-contained blocks x 512 rows.
// read all partials -> barrier -> write idx/quantized/loss.
__global__ __launch_bounds__(512) void vq_merge(const float* __restrict__ w,
                                                float* __restrict__ out) {
  const int tid = threadIdx.x;
  const int row = blockIdx.x * 512 + tid;
  const float* gp = out + (size_t)blockIdx.x * 32768;

  const float2 c0 = *(const float2*)(gp + 0 * 1024 + 2 * tid);
  const float2 c1 = *(const float2*)(gp + 1 * 1024 + 2 * tid);
  const float2 c2 = *(const float2*)(gp + 2 * 1024 + 2 * tid);
  const float2 c3 = *(const float2*)(gp + 3 * 1024 + 2 * tid);
  const float xn = gp[4096 + tid];

  float s = c0.x;
  float fi = c0.y;
  if (c1.x > s) { s = c1.x; fi = c1.y; }   // strict > keeps earlier slice (smaller idx)
  if (c2.x > s) { s = c2.x; fi = c2.y; }
  if (c3.x > s) { s = c3.x; fi = c3.y; }

  __syncthreads();   // all partial reads complete before any overwrite below

  out[OFF_IDX + row] = fi;
  const int bi = (int)fi;
  const float4* qs = (const float4*)(w + (size_t)bi * D);
  float4* qd = (float4*)(out + OFF_Q + (size_t)row * D);
#pragma unroll
  for (int i = 0; i < 16; ++i) qd[i] = qs[i];

  float lr = xn - 2.f * s;   // ||x - w_bi||^2 = ||x||^2 - 2*(x.w - 0.5||w||^2)
#pragma unroll
  for (int off = 32; off >= 1; off >>= 1) lr += __shfl_xor(lr, off, 64);
  if ((tid & 63) == 0) atomicAdd(out + OFF_LOSS, lr * (BETA / (float)(N_VEC * D)));
}

extern "C" void kernel_launch(void* const* d_in, const int* in_sizes, int n_in,
                              void* d_out, int out_size, void* d_ws, size_t ws_size,
                              hipStream_t stream) {
  const float* x = (const float*)d_in[0];
  const float* w = (const float*)d_in[1];
  float* out = (float*)d_out;
  char* ws = (char*)d_ws;

  vq_prep<<<32, 256, 0, stream>>>(w, ws, out);
  vq_scan<<<(N_VEC / ROWS_PB) * 4, 256, 0, stream>>>(x, ws, out);
  vq_merge<<<N_VEC / 512, 512, 0, stream>>>(w, out);
}

// Round 7
// 118.382 us; speedup vs baseline: 2.8274x; 1.0032x over previous
//
#include <hip/hip_runtime.h>

// VQ-VAE VectorQuantizer forward, MI355X (gfx950)
// Round 7: + XCD sibling co-location swizzle (slice-siblings share L2),
//          chunked self-contained partials, coalesced cooperative merge.
// out (f32 flat): [0..4194304) quantized, [4194304] loss,
//                 [4194305..+65536) indices (as float), [4259841..+65536) w.T

#define N_VEC 65536
#define D 64
#define K 1024
#define BETA 0.25f

#define OFF_Q    0
#define OFF_LOSS 4194304
#define OFF_IDX  4194305
#define OFF_WT   4259841

#define WS_WHI  0         // 128 KB frag-ordered fp16 hi plane
#define WS_WLO  131072    // 128 KB lo plane
#define WS_HNEG 262144    // 4 KB  -0.5*||w||^2 (f32)

typedef _Float16 v8h __attribute__((ext_vector_type(8)));
typedef float v16f __attribute__((ext_vector_type(16)));
typedef __attribute__((address_space(3))) void lds_void_t;
typedef __attribute__((address_space(1))) const void gbl_void_t;

// ---------------- prep (proven): w^T, frag fp16 hi/lo, hneg, loss=0
__global__ __launch_bounds__(256) void vq_prep(const float* __restrict__ w,
                                               char* __restrict__ ws,
                                               float* __restrict__ out) {
  __shared__ float s[2048];
  const int t = blockIdx.x, tid = threadIdx.x;

  const float4* src = (const float4*)(w + (size_t)t * 2048);
  float4 a = src[tid];
  float4 b = src[tid + 256];
  ((float4*)s)[tid] = a;
  ((float4*)s)[tid + 256] = b;

  float p0 = a.x * a.x + a.y * a.y + a.z * a.z + a.w * a.w;
  float p1 = b.x * b.x + b.y * b.y + b.z * b.z + b.w * b.w;
#pragma unroll
  for (int m = 1; m <= 8; m <<= 1) {
    p0 += __shfl_xor(p0, m, 64);
    p1 += __shfl_xor(p1, m, 64);
  }
  float* hn = (float*)(ws + WS_HNEG);
  if ((tid & 15) == 0) {
    hn[t * 32 + (tid >> 4)] = -0.5f * p0;
    hn[t * 32 + 16 + (tid >> 4)] = -0.5f * p1;
  }
  if (t == 0 && tid == 0) out[OFF_LOSS] = 0.f;
  __syncthreads();

  { // frag order: ((t*4+ks)*64 + l)*16B <-> w[t*32+(l&31)][ks*16+(l>>5)*8+j]
    const int ks = tid >> 6, l = tid & 63;
    const float* r0 = s + (l & 31) * 64 + ks * 16 + ((l >> 5) << 3);
    v8h hv, lv;
#pragma unroll
    for (int j = 0; j < 8; ++j) {
      float v = r0[j];
      _Float16 h = (_Float16)v;
      hv[j] = h;
      lv[j] = (_Float16)(v - (float)h);
    }
    const size_t eoff = ((size_t)(t * 4 + ks) * 64 + l) * 16;
    *(v8h*)(ws + WS_WHI + eoff) = hv;
    *(v8h*)(ws + WS_WLO + eoff) = lv;
  }

  { // w^T
    const int d = tid >> 2, k0 = (tid & 3) * 8;
#pragma unroll
    for (int j = 0; j < 8; ++j)
      out[OFF_WT + d * 1024 + t * 32 + k0 + j] = s[(k0 + j) * 64 + d];
  }
}

// ---------------- scan: 512 blocks; XCD swizzle co-locates a row-group's 4
// slice-siblings on one XCD (L2 shares the 128 KB x panel). 4 waves/block,
// slice (256 codes) resident in LDS, swapped-operand MFMA (A=w, B=x).
// Partials per 256-row chunk: floats [chunk + slice*512, +512) = 256 x
// (score, idxf); xn at [chunk + 2048, +256). chunk = row0*64.
#define ROWS_PB 512

__global__ __launch_bounds__(256, 2) void vq_scan(const float* __restrict__ x,
                                                  const char* __restrict__ ws,
                                                  float* __restrict__ out) {
  __shared__ __align__(16) char lds[72704];
  const int tid = threadIdx.x;
  const int wv = tid >> 6, ln = tid & 63;
  const int col = ln & 31, hi = ln >> 5;

  // XCD sibling co-location: siblings (same group, slices 0-3) are bids
  // congruent mod 8 -> same XCD under round-robin dispatch.
  const int bid = blockIdx.x;               // 0..511
  const int xcd = bid & 7, ii = bid >> 3;   // ii: 0..63
  const int grp = xcd * 16 + (ii & 15);     // 0..127
  const int slice = ii >> 4;                // 0..3
  const int rowsBlock = grp * ROWS_PB;

  // ---- stage slice once (wave-uniform LDS base + per-lane global)
  {
    const char* gH = ws + WS_WHI + slice * 32768;
    const char* gL = ws + WS_WLO + slice * 32768;
#pragma unroll
    for (int it = 0; it < 8; ++it) {
      const unsigned off = (unsigned)(it * 4096 + wv * 1024);
      __builtin_amdgcn_global_load_lds((gbl_void_t*)(gH + off + ln * 16),
                                       (lds_void_t*)(lds + off), 16, 0, 0);
      __builtin_amdgcn_global_load_lds((gbl_void_t*)(gL + off + ln * 16),
                                       (lds_void_t*)(lds + 32768 + off), 16, 0, 0);
    }
    if (wv == 0)
      __builtin_amdgcn_global_load_lds((gbl_void_t*)(ws + WS_HNEG + slice * 1024 + ln * 16),
                                       (lds_void_t*)(lds + 65536), 16, 0, 0);
  }
  asm volatile("s_waitcnt vmcnt(0)" ::: "memory");
  __syncthreads();

  const float* hn = (const float*)(lds + 65536);
  float2* s_part = (float2*)(lds + 66560);   // 512 x (score, idxf)
  float* s_xn = (float*)(lds + 70656);       // 512 x ||x||^2

  // ones B-frag for the bias MFMA: B[k][*]=1 at k=0,1
  v8h ones = {};
  ones[0] = hi ? (_Float16)0.f : (_Float16)1.f;
  ones[1] = hi ? (_Float16)0.f : (_Float16)1.f;

#pragma unroll 1
  for (int pp = 0; pp < 2; ++pp) {
    const int rows0 = rowsBlock + wv * 128 + pp * 64;

    // ---- x B-frags for 2 tiles (fp16 hi/lo split) + ||x||^2 partials
    v8h xh0[4], xl0[4], xh1[4], xl1[4];
    float xn0 = 0.f, xn1 = 0.f;
    {
      const float* xr0 = x + (size_t)(rows0 + col) * D + hi * 8;
      const float* xr1 = x + (size_t)(rows0 + 32 + col) * D + hi * 8;
#pragma unroll
      for (int ks = 0; ks < 4; ++ks) {
        float4 u0 = *(const float4*)(xr0 + ks * 16);
        float4 u1 = *(const float4*)(xr0 + ks * 16 + 4);
        float4 v0 = *(const float4*)(xr1 + ks * 16);
        float4 v1 = *(const float4*)(xr1 + ks * 16 + 4);
        float e0[8] = {u0.x, u0.y, u0.z, u0.w, u1.x, u1.y, u1.z, u1.w};
        float e1[8] = {v0.x, v0.y, v0.z, v0.w, v1.x, v1.y, v1.z, v1.w};
#pragma unroll
        for (int j = 0; j < 8; ++j) {
          _Float16 h0 = (_Float16)e0[j];
          xh0[ks][j] = h0;
          xl0[ks][j] = (_Float16)(e0[j] - (float)h0);
          xn0 = fmaf(e0[j], e0[j], xn0);
          _Float16 h1 = (_Float16)e1[j];
          xh1[ks][j] = h1;
          xl1[ks][j] = (_Float16)(e1[j] - (float)h1);
          xn1 = fmaf(e1[j], e1[j], xn1);
        }
      }
    }

    float best0 = -3.0e38f, best1 = -3.0e38f;
    int bi0 = 0, bi1 = 0;

#pragma unroll 2
    for (int ct = 0; ct < 8; ++ct) {
      v8h wh[4], wl[4];
#pragma unroll
      for (int ks = 0; ks < 4; ++ks) {
        wh[ks] = *(const v8h*)(lds + ct * 4096 + ks * 1024 + ln * 16);
        wl[ks] = *(const v8h*)(lds + 32768 + ct * 4096 + ks * 1024 + ln * 16);
      }
      const float hv = hn[ct * 32 + col];
      const _Float16 bh = (_Float16)hv;
      const _Float16 bl = (_Float16)(hv - (float)bh);
      v8h bias = {};
      bias[0] = hi ? (_Float16)0.f : bh;
      bias[1] = hi ? (_Float16)0.f : bl;

      v16f a0 = {}, a1 = {};
      a0 = __builtin_amdgcn_mfma_f32_32x32x16_f16(bias, ones, a0, 0, 0, 0);
      a1 = __builtin_amdgcn_mfma_f32_32x32x16_f16(bias, ones, a1, 0, 0, 0);
#pragma unroll
      for (int ks = 0; ks < 4; ++ks) {
        a0 = __builtin_amdgcn_mfma_f32_32x32x16_f16(wh[ks], xh0[ks], a0, 0, 0, 0);
        a1 = __builtin_amdgcn_mfma_f32_32x32x16_f16(wh[ks], xh1[ks], a1, 0, 0, 0);
        a0 = __builtin_amdgcn_mfma_f32_32x32x16_f16(wl[ks], xh0[ks], a0, 0, 0, 0);
        a1 = __builtin_amdgcn_mfma_f32_32x32x16_f16(wl[ks], xh1[ks], a1, 0, 0, 0);
        a0 = __builtin_amdgcn_mfma_f32_32x32x16_f16(wh[ks], xl0[ks], a0, 0, 0, 0);
        a1 = __builtin_amdgcn_mfma_f32_32x32x16_f16(wh[ks], xl1[ks], a1, 0, 0, 0);
      }

      float m0 = fmaxf(fmaxf(fmaxf(a0[0], a0[1]), fmaxf(a0[2], a0[3])),
                       fmaxf(fmaxf(a0[4], a0[5]), fmaxf(a0[6], a0[7])));
      m0 = fmaxf(m0, fmaxf(fmaxf(fmaxf(a0[8], a0[9]), fmaxf(a0[10], a0[11])),
                           fmaxf(fmaxf(a0[12], a0[13]), fmaxf(a0[14], a0[15]))));
      float m1 = fmaxf(fmaxf(fmaxf(a1[0], a1[1]), fmaxf(a1[2], a1[3])),
                       fmaxf(fmaxf(a1[4], a1[5]), fmaxf(a1[6], a1[7])));
      m1 = fmaxf(m1, fmaxf(fmaxf(fmaxf(a1[8], a1[9]), fmaxf(a1[10], a1[11])),
                           fmaxf(fmaxf(a1[12], a1[13]), fmaxf(a1[14], a1[15]))));
      const bool u0 = m0 > best0;
      const bool u1 = m1 > best1;
      if (__any(u0 || u1)) {
        const int cbase = slice * 256 + ct * 32 + 4 * hi;
#pragma unroll
        for (int r = 15; r >= 0; --r) {   // descending overwrite => first max wins
          const int code = cbase + (r & 3) + 8 * (r >> 2);
          bi0 = (u0 && a0[r] == m0) ? code : bi0;
          bi1 = (u1 && a1[r] == m1) ? code : bi1;
        }
        best0 = u0 ? m0 : best0;
        best1 = u1 ? m1 : best1;
      }
    }

    { // merge the two hi-halves
      float ob = __shfl_xor(best0, 32, 64);
      int oi = __shfl_xor(bi0, 32, 64);
      if (ob > best0 || (ob == best0 && oi < bi0)) { best0 = ob; bi0 = oi; }
      ob = __shfl_xor(best1, 32, 64);
      oi = __shfl_xor(bi1, 32, 64);
      if (ob > best1 || (ob == best1 && oi < bi1)) { best1 = ob; bi1 = oi; }
      xn0 += __shfl_xor(xn0, 32, 64);
      xn1 += __shfl_xor(xn1, 32, 64);
    }

    const int rl = wv * 128 + pp * 64 + hi * 32 + col;
    s_part[rl] = make_float2(hi ? best1 : best0, (float)(hi ? bi1 : bi0));
    if (slice == 0) s_xn[rl] = hi ? xn1 : xn0;
  }
  __syncthreads();

  // ---- coalesced publish into two self-contained 256-row chunks
  {
    const float4* sp4 = (const float4*)s_part;   // 256 float4
    const int h = tid >> 7, j = tid & 127;
    float* chunk = out + (size_t)(rowsBlock + h * 256) * 64;
    ((float4*)(chunk + slice * 512))[j] = sp4[tid];
    if (slice == 0 && (tid & 127) < 64) {
      const float4* sx4 = (const float4*)s_xn;   // 128 float4
      ((float4*)(chunk + 2048))[tid & 63] = sx4[h * 64 + (tid & 63)];
    }
  }
}

// ---------------- merge: 256 self-contained blocks x 256 rows.
// phase 1: coalesced partial reads -> winner, idx, loss.
// phase 2: cooperative gather-copy, 4 rows x 64 lanes = 1 KB per instruction.
__global__ __launch_bounds__(256) void vq_merge(const float* __restrict__ w,
                                                float* __restrict__ out) {
  __shared__ int s_bi[256];
  const int tid = threadIdx.x;
  const int base = blockIdx.x * 256;
  float* cb = out + (size_t)blockIdx.x * 16384;

  const float2 c0 = *(const float2*)(cb + 0 * 512 + 2 * tid);
  const float2 c1 = *(const float2*)(cb + 1 * 512 + 2 * tid);
  const float2 c2 = *(const float2*)(cb + 2 * 512 + 2 * tid);
  const float2 c3 = *(const float2*)(cb + 3 * 512 + 2 * tid);
  const float xn = cb[2048 + tid];

  float s = c0.x;
  float fi = c0.y;
  if (c1.x > s) { s = c1.x; fi = c1.y; }   // strict > keeps earlier slice (smaller idx)
  if (c2.x > s) { s = c2.x; fi = c2.y; }
  if (c3.x > s) { s = c3.x; fi = c3.y; }

  out[OFF_IDX + base + tid] = fi;
  s_bi[tid] = (int)fi;

  float lr = xn - 2.f * s;   // ||x - w_bi||^2 = ||x||^2 - 2*(x.w - 0.5||w||^2)
#pragma unroll
  for (int off = 32; off >= 1; off >>= 1) lr += __shfl_xor(lr, off, 64);
  if ((tid & 63) == 0) atomicAdd(out + OFF_LOSS, lr * (BETA / (float)(N_VEC * D)));

  __syncthreads();   // also orders partial reads before quantized overwrite

  const int wv = tid >> 6, ln = tid & 63;
#pragma unroll 8
  for (int it = 0; it < 64; ++it) {
    const int rl = it * 4 + wv;
    const float v = w[(size_t)s_bi[rl] * 64 + ln];
    out[(size_t)(base + rl) * 64 + ln] = v;
  }
}

extern "C" void kernel_launch(void* const* d_in, const int* in_sizes, int n_in,
                              void* d_out, int out_size, void* d_ws, size_t ws_size,
                              hipStream_t stream) {
  const float* x = (const float*)d_in[0];
  const float* w = (const float*)d_in[1];
  float* out = (float*)d_out;
  char* ws = (char*)d_ws;

  vq_prep<<<32, 256, 0, stream>>>(w, ws, out);
  vq_scan<<<(N_VEC / ROWS_PB) * 4, 256, 0, stream>>>(x, ws, out);
  vq_merge<<<N_VEC / 256, 256, 0, stream>>>(w, out);
}